// Round 5
// baseline (181.684 us; speedup 1.0000x reference)
//
#include <hip/hip_runtime.h>
#include <hip/hip_bf16.h>

#define N_NODES 50000
#define N_EDGES 800000
#define IN_DIM  256
#define OUT_DIM 128

#define NBINS        256      // bins of 196 rows: 256*196 = 50176 >= 50000
#define ROWS_PER_BIN 196
#define BIN_CAP      3600     // mean 3125 + 8.5 sigma
#define EPB          2048     // edges per bin-block
#define NB_BIN       391      // ceil(800000/2048)
#define GEMM_GRID    512      // persistent gemm: 2 blocks/CU, stride 2048 tiles
#define CUR_STRIDE   32       // one 128B cacheline per bin cursor

typedef __bf16 bf16x8 __attribute__((ext_vector_type(8)));
typedef float  f32x4  __attribute__((ext_vector_type(4)));

// bin = floor(row/196) via magic: (r*85599)>>24, exact for r < 50176 (verified R5-R7)
__device__ __forceinline__ unsigned bin_of(unsigned r) { return (r * 85599u) >> 24; }
__device__ __forceinline__ float blo(unsigned u) { return __uint_as_float(u << 16); }
__device__ __forceinline__ float bhi(unsigned u) { return __uint_as_float(u & 0xffff0000u); }

// ---------------------------------------------------------------------------
// ws layout (bytes)
// ---------------------------------------------------------------------------
#define WF_OFF   0                      // 64 KB    : Wf bf16 frag-order [4096 slots][8]
#define SUP_OFF  65536                  // 12.8 MB  : support u32 [50000][64] planar-pair
#define BIN_OFF  12865536               // 7.37 MB  : binbuf int2[256*3600]
#define CUR_OFF  20238336               // 32 KB    : bin_cursor int[256*CUR_STRIDE]

// ---------------------------------------------------------------------------
// prep (R12, verified): Wf = W in MFMA B-fragment order.
// Slot s (16B = 8 halfs): n = s>>9, ks = (s>>6)&7, lane = s&63, m = lane&15,
// quad = (lane>>4); half j holds W[(quad*8+ks*32+j)*OUT_DIM + (n*16+m)].
// ---------------------------------------------------------------------------
__global__ void k_prep(const float* __restrict__ W, __bf16* __restrict__ Wf,
                       int* __restrict__ bin_cursor) {
    int t = blockIdx.x * 256 + threadIdx.x;
    if (t < 32768) {
        int s = t >> 3, j = t & 7;
        int nrow = ((s >> 9) << 4) | (s & 15);                 // n*16 + m
        int k    = (((s >> 4) & 3) << 3) | (((s >> 6) & 7) << 5) | j;
        Wf[t] = (__bf16)W[k * OUT_DIM + nrow];
    }
    if (t < NBINS) bin_cursor[t * CUR_STRIDE] = t * BIN_CAP;
}

// ---------------------------------------------------------------------------
// k_bin (verified R10/R12): one-pass lean binning.
// ---------------------------------------------------------------------------
__global__ __launch_bounds__(256) void k_bin(const int* __restrict__ rows,
                                             const int* __restrict__ cols,
                                             const float* __restrict__ vals,
                                             int* __restrict__ bin_cursor,
                                             int2* __restrict__ binbuf) {
    __shared__ int s_cur[NBINS];
    __shared__ int s_base[NBINS];
    int t = threadIdx.x;

    long e0 = (long)blockIdx.x * EPB;
    s_cur[t] = 0;
    __syncthreads();

    int2 rec[8];
    int  lrank[8];
    bool full = (e0 + EPB <= N_EDGES);   // true for 390 of 391 blocks

    if (full) {
#pragma unroll
        for (int k = 0; k < 8; ++k) {
            long e = e0 + k * 256 + t;
            unsigned r = (unsigned)rows[e];
            unsigned c = (unsigned)cols[e];
            float    w = vals[e];
            rec[k]   = make_int2((int)((r << 16) | c), __float_as_int(w));
            lrank[k] = atomicAdd(&s_cur[bin_of(r)], 1);
        }
    } else {
#pragma unroll
        for (int k = 0; k < 8; ++k) {
            long e = e0 + k * 256 + t;
            lrank[k] = -1;
            if (e < N_EDGES) {
                unsigned r = (unsigned)rows[e];
                unsigned c = (unsigned)cols[e];
                float    w = vals[e];
                rec[k]   = make_int2((int)((r << 16) | c), __float_as_int(w));
                lrank[k] = atomicAdd(&s_cur[bin_of(r)], 1);
            }
        }
    }
    __syncthreads();

    s_base[t] = atomicAdd(&bin_cursor[t * CUR_STRIDE], s_cur[t]);
    __syncthreads();

    if (full) {
#pragma unroll
        for (int k = 0; k < 8; ++k) {
            unsigned bn = bin_of(((unsigned)rec[k].x) >> 16);
            int dst = s_base[bn] + lrank[k];
            if (dst < (int)(bn + 1) * BIN_CAP)
                binbuf[dst] = rec[k];
        }
    } else {
#pragma unroll
        for (int k = 0; k < 8; ++k) {
            if (lrank[k] >= 0) {
                unsigned bn = bin_of(((unsigned)rec[k].x) >> 16);
                int dst = s_base[bn] + lrank[k];
                if (dst < (int)(bn + 1) * BIN_CAP)
                    binbuf[dst] = rec[k];
            }
        }
    }
}

// ---------------------------------------------------------------------------
// k_gemm (R13): PERSISTENT.  512 blocks stage the 64 KB frag-order Wf into
// LDS once, then each wave loops over tiles (stride GEMM_GRID*4 = 2048).
// Saves 270 redundant Wf stagings vs R12 and overlaps tile i+1's 16 A-loads
// with tile i's epilogue.  Fragment roles + planar-pair epilogue = verified
// R7/R12 mapping, untouched.
// ---------------------------------------------------------------------------
__global__ __launch_bounds__(256, 2) void k_gemm(const float* __restrict__ x,
                                                 const __bf16* __restrict__ Wf,
                                                 unsigned* __restrict__ sup32) {
    __shared__ uint4 sB[4096];                     // 64 KB: all of Wf
    int t = threadIdx.x;

    const uint4* wf4 = (const uint4*)Wf;
#pragma unroll
    for (int r = 0; r < 16; ++r) sB[r * 256 + t] = wf4[r * 256 + t];
    __syncthreads();

    int wave = t >> 6;
    int lane = t & 63;
    int m    = lane & 15;
    int quad = lane >> 4;
    const __bf16* sbh = (const __bf16*)sB;

    for (long tile = (long)blockIdx.x * 4 + wave; tile < 3125;
         tile += (long)GEMM_GRID * 4) {
        // A: lane (m,quad) reads row tile*16+m, bytes quad*32 + ks*128.
        // 3125*16 == 50000 -> every row in-bounds, no guard.
        const float* aprow = x + (tile * 16 + m) * IN_DIM + quad * 8;

        float4 fa[16];
#pragma unroll
        for (int ks = 0; ks < 8; ++ks) {
            fa[2 * ks]     = *(const float4*)(aprow + ks * 32);
            fa[2 * ks + 1] = *(const float4*)(aprow + ks * 32 + 4);
        }
        bf16x8 ab[8];
#pragma unroll
        for (int ks = 0; ks < 8; ++ks) {
            float4 f0 = fa[2 * ks];
            float4 f1 = fa[2 * ks + 1];
            ab[ks] = (bf16x8){(__bf16)f0.x, (__bf16)f0.y, (__bf16)f0.z, (__bf16)f0.w,
                              (__bf16)f1.x, (__bf16)f1.y, (__bf16)f1.z, (__bf16)f1.w};
        }

        f32x4 acc[8];
#pragma unroll
        for (int n = 0; n < 8; ++n) acc[n] = (f32x4){0, 0, 0, 0};

#pragma unroll
        for (int ks = 0; ks < 8; ++ks) {
#pragma unroll
            for (int n = 0; n < 8; ++n) {
                // slot (n*8+ks)*64 + lane : consecutive lanes -> consecutive 16B
                bf16x8 bfr = *(const bf16x8*)(sbh + (((n * 8 + ks) * 64 + lane) << 3));
                acc[n] = __builtin_amdgcn_mfma_f32_16x16x32_bf16(ab[ks], bfr, acc[n], 0, 0, 0);
            }
        }

        // planar-pair epilogue (verified R7): word j = n*16+m = ch j | ch j+64
        unsigned* op = sup32 + (long)tile * 16 * 64;
#pragma unroll
        for (int r = 0; r < 4; ++r) {
#pragma unroll
            for (int n = 0; n < 4; ++n) {
                __bf16 lo = (__bf16)acc[n][r], hi = (__bf16)acc[n + 4][r];
                unsigned w = (unsigned)*(unsigned short*)&lo |
                             ((unsigned)*(unsigned short*)&hi << 16);
                op[(quad * 4 + r) * 64 + n * 16 + m] = w;
            }
        }
    }
}

// ---------------------------------------------------------------------------
// k_sg (R13): gather widened to 16 loads in flight (avg row degree = 16 ->
// most rows finish in ONE latency round instead of two).  Same predicated
// logic as the verified 8-wide version; all indexing static after unroll.
// ---------------------------------------------------------------------------
__global__ __launch_bounds__(1024) void k_sg(const int* __restrict__ bin_cursor,
                                             const int2* __restrict__ binbuf,
                                             const unsigned* __restrict__ sup,
                                             const float* __restrict__ bias,
                                             float* __restrict__ out) {
    __shared__ int2 stage[BIN_CAP];                // 28.8 KB
    __shared__ int2 sorted_[BIN_CAP];              // 28.8 KB
    __shared__ int  cnt[256], off[256], cur[256], s[256];
    int b = blockIdx.x, t = threadIdx.x;
    int row0 = b * ROWS_PER_BIN;

    int n = bin_cursor[b * CUR_STRIDE] - b * BIN_CAP;
    n = n < 0 ? 0 : (n > BIN_CAP ? BIN_CAP : n);
    const int2* seg = binbuf + (long)b * BIN_CAP;

    if (t < 256) cnt[t] = 0;
    __syncthreads();

    for (int i = t; i < n; i += 1024) {
        int2 rec = seg[i];
        stage[i] = rec;
        atomicAdd(&cnt[(int)(((unsigned)rec.x) >> 16) - row0], 1);
    }
    __syncthreads();

    int v = 0;
    if (t < 256) { v = cnt[t]; s[t] = v; }
    __syncthreads();
#pragma unroll
    for (int o = 1; o < 256; o <<= 1) {
        int xv = 0;
        if (t < 256 && t >= o) xv = s[t - o];
        __syncthreads();
        if (t < 256) s[t] += xv;
        __syncthreads();
    }
    if (t < 256) { off[t] = s[t] - v; cur[t] = 0; }
    __syncthreads();

    for (int i = t; i < n; i += 1024) {
        int2 rec = stage[i];
        int rl = (int)(((unsigned)rec.x) >> 16) - row0;
        sorted_[off[rl] + atomicAdd(&cur[rl], 1)] = rec;
    }
    __syncthreads();

    int wave = t >> 6, lane = t & 63;
    float bb0 = bias[lane], bb1 = bias[64 + lane];

    for (int rl = wave; rl < ROWS_PER_BIN; rl += 16) {
        int row = row0 + rl;
        if (row >= N_NODES) continue;
        int st = off[rl], nd = cnt[rl];
        float a0 = 0.f, a1 = 0.f;
        for (int i = 0; i < nd; i += 16) {
            int2 e[16]; unsigned u[16]; float vv[16];
#pragma unroll
            for (int j = 0; j < 16; ++j) {
                int ok = (i + j) < nd;
                e[j]  = sorted_[ok ? st + i + j : st];
                vv[j] = ok ? __int_as_float(e[j].y) : 0.f;
            }
#pragma unroll
            for (int j = 0; j < 16; ++j)
                u[j] = sup[(long)(((unsigned)e[j].x) & 0xffffu) * 64 + lane];
#pragma unroll
            for (int j = 0; j < 16; ++j) {
                a0 += vv[j] * blo(u[j]);
                a1 += vv[j] * bhi(u[j]);
            }
        }
        out[(long)row * 128 + lane]      = a0 + bb0;
        out[(long)row * 128 + 64 + lane] = a1 + bb1;
    }
}

// ---------------------------------------------------------------------------
extern "C" void kernel_launch(void* const* d_in, const int* in_sizes, int n_in,
                              void* d_out, int out_size, void* d_ws, size_t ws_size,
                              hipStream_t stream) {
    const int*   adj_rows = (const int*)  d_in[0];
    const int*   adj_cols = (const int*)  d_in[1];
    const float* adj_vals = (const float*)d_in[2];
    const float* x        = (const float*)d_in[3];
    const float* W        = (const float*)d_in[4];
    const float* b        = (const float*)d_in[5];
    float* out = (float*)d_out;

    char* ws = (char*)d_ws;
    __bf16*   Wf         = (__bf16*)  (ws + WF_OFF);
    unsigned* sup32      = (unsigned*)(ws + SUP_OFF);
    int2*     binbuf     = (int2*)    (ws + BIN_OFF);
    int*      bin_cursor = (int*)     (ws + CUR_OFF);

    k_prep<<<128, 256, 0, stream>>>(W, Wf, bin_cursor);
    k_bin <<<NB_BIN, 256, 0, stream>>>(adj_rows, adj_cols, adj_vals,
                                       bin_cursor, binbuf);
    k_gemm<<<GEMM_GRID, 256, 0, stream>>>(x, Wf, sup32);
    k_sg  <<<NBINS, 1024, 0, stream>>>(bin_cursor, binbuf, sup32, b, out);
}

// Round 6
// 162.710 us; speedup vs baseline: 1.1166x; 1.1166x over previous
//
#include <hip/hip_runtime.h>
#include <hip/hip_bf16.h>

#define N_NODES 50000
#define N_EDGES 800000
#define IN_DIM  256
#define OUT_DIM 128

#define NBINS        512      // R14: bins of 98 rows: 512*98 = 50176 >= 50000
#define ROWS_PER_BIN 98
#define BIN_CAP      1920     // mean 1563 + 9 sigma
#define EPB          2048     // edges per bin-block
#define NB_BIN       391      // ceil(800000/2048)
#define NB_GEMM      782      // R12 gemm: 1 wave = 1 tile, 4 tiles/block
#define CUR_STRIDE   32       // one 128B cacheline per bin cursor

typedef __bf16 bf16x8 __attribute__((ext_vector_type(8)));
typedef float  f32x4  __attribute__((ext_vector_type(4)));

// R14 bin = floor(row/98) via magic: (r*85599)>>23, exact for r < 50176
// (same verified constant as R5-R7's /196 magic, shift 24->23; max product
// 50175*85599 = 4294929825 < 2^32).
__device__ __forceinline__ unsigned bin_of(unsigned r) { return (r * 85599u) >> 23; }
__device__ __forceinline__ float blo(unsigned u) { return __uint_as_float(u << 16); }
__device__ __forceinline__ float bhi(unsigned u) { return __uint_as_float(u & 0xffff0000u); }

// ---------------------------------------------------------------------------
// ws layout (bytes)
// ---------------------------------------------------------------------------
#define WF_OFF   0                      // 64 KB    : Wf bf16 frag-order [4096 slots][8]
#define SUP_OFF  65536                  // 12.8 MB  : support u32 [50000][64] planar-pair
#define BIN_OFF  12865536               // 7.86 MB  : binbuf int2[512*1920]
#define CUR_OFF  20729856               // 64 KB    : bin_cursor int[512*CUR_STRIDE]

// ---------------------------------------------------------------------------
// prep (R12, verified): Wf = W in MFMA B-fragment order.
// Slot s (16B = 8 halfs): n = s>>9, ks = (s>>6)&7, lane = s&63, m = lane&15,
// quad = (lane>>4); half j holds W[(quad*8+ks*32+j)*OUT_DIM + (n*16+m)].
// ---------------------------------------------------------------------------
__global__ void k_prep(const float* __restrict__ W, __bf16* __restrict__ Wf,
                       int* __restrict__ bin_cursor) {
    int t = blockIdx.x * 256 + threadIdx.x;
    if (t < 32768) {
        int s = t >> 3, j = t & 7;
        int nrow = ((s >> 9) << 4) | (s & 15);                 // n*16 + m
        int k    = (((s >> 4) & 3) << 3) | (((s >> 6) & 7) << 5) | j;
        Wf[t] = (__bf16)W[k * OUT_DIM + nrow];
    }
    if (t < NBINS) bin_cursor[t * CUR_STRIDE] = t * BIN_CAP;
}

// ---------------------------------------------------------------------------
// k_bin (verified R10/R12 structure, 512 bins): one-pass lean binning.
// ---------------------------------------------------------------------------
__global__ __launch_bounds__(256) void k_bin(const int* __restrict__ rows,
                                             const int* __restrict__ cols,
                                             const float* __restrict__ vals,
                                             int* __restrict__ bin_cursor,
                                             int2* __restrict__ binbuf) {
    __shared__ int s_cur[NBINS];
    __shared__ int s_base[NBINS];
    int t = threadIdx.x;

    long e0 = (long)blockIdx.x * EPB;
    s_cur[t] = 0; s_cur[t + 256] = 0;
    __syncthreads();

    int2 rec[8];
    int  lrank[8];
    bool full = (e0 + EPB <= N_EDGES);   // true for 390 of 391 blocks

    if (full) {
#pragma unroll
        for (int k = 0; k < 8; ++k) {
            long e = e0 + k * 256 + t;
            unsigned r = (unsigned)rows[e];
            unsigned c = (unsigned)cols[e];
            float    w = vals[e];
            rec[k]   = make_int2((int)((r << 16) | c), __float_as_int(w));
            lrank[k] = atomicAdd(&s_cur[bin_of(r)], 1);
        }
    } else {
#pragma unroll
        for (int k = 0; k < 8; ++k) {
            long e = e0 + k * 256 + t;
            lrank[k] = -1;
            if (e < N_EDGES) {
                unsigned r = (unsigned)rows[e];
                unsigned c = (unsigned)cols[e];
                float    w = vals[e];
                rec[k]   = make_int2((int)((r << 16) | c), __float_as_int(w));
                lrank[k] = atomicAdd(&s_cur[bin_of(r)], 1);
            }
        }
    }
    __syncthreads();

    s_base[t]       = atomicAdd(&bin_cursor[t * CUR_STRIDE], s_cur[t]);
    s_base[t + 256] = atomicAdd(&bin_cursor[(t + 256) * CUR_STRIDE], s_cur[t + 256]);
    __syncthreads();

    if (full) {
#pragma unroll
        for (int k = 0; k < 8; ++k) {
            unsigned bn = bin_of(((unsigned)rec[k].x) >> 16);
            int dst = s_base[bn] + lrank[k];
            if (dst < (int)(bn + 1) * BIN_CAP)
                binbuf[dst] = rec[k];
        }
    } else {
#pragma unroll
        for (int k = 0; k < 8; ++k) {
            if (lrank[k] >= 0) {
                unsigned bn = bin_of(((unsigned)rec[k].x) >> 16);
                int dst = s_base[bn] + lrank[k];
                if (dst < (int)(bn + 1) * BIN_CAP)
                    binbuf[dst] = rec[k];
            }
        }
    }
}

// ---------------------------------------------------------------------------
// k_gemm: reverted to verified R12 (best measured total).  Whole block stages
// 64 KB frag-order Wf -> LDS; 1 wave = 1 tile of 16 rows; 16 A-loads then
// bf16 conversion; zero-conflict stride-1 ds_read_b128 B; planar-pair
// epilogue (verified R7 mapping).
// ---------------------------------------------------------------------------
__global__ __launch_bounds__(256, 2) void k_gemm(const float* __restrict__ x,
                                                 const __bf16* __restrict__ Wf,
                                                 unsigned* __restrict__ sup32) {
    __shared__ uint4 sB[4096];                     // 64 KB: all of Wf
    int t = threadIdx.x;

    const uint4* wf4 = (const uint4*)Wf;
#pragma unroll
    for (int r = 0; r < 16; ++r) sB[r * 256 + t] = wf4[r * 256 + t];
    __syncthreads();

    int  wave = t >> 6;
    int  lane = t & 63;
    long tile = (long)blockIdx.x * 4 + wave;       // 0..3127
    if (tile >= 3125) return;                      // after the barrier: safe
    int  m    = lane & 15;
    int  quad = lane >> 4;

    const float* aprow = x + (tile * 16 + m) * IN_DIM + quad * 8;

    float4 fa[16];
#pragma unroll
    for (int ks = 0; ks < 8; ++ks) {
        fa[2 * ks]     = *(const float4*)(aprow + ks * 32);
        fa[2 * ks + 1] = *(const float4*)(aprow + ks * 32 + 4);
    }
    bf16x8 ab[8];
#pragma unroll
    for (int ks = 0; ks < 8; ++ks) {
        float4 f0 = fa[2 * ks];
        float4 f1 = fa[2 * ks + 1];
        ab[ks] = (bf16x8){(__bf16)f0.x, (__bf16)f0.y, (__bf16)f0.z, (__bf16)f0.w,
                          (__bf16)f1.x, (__bf16)f1.y, (__bf16)f1.z, (__bf16)f1.w};
    }

    f32x4 acc[8];
#pragma unroll
    for (int n = 0; n < 8; ++n) acc[n] = (f32x4){0, 0, 0, 0};

    const __bf16* sbh = (const __bf16*)sB;
#pragma unroll
    for (int ks = 0; ks < 8; ++ks) {
#pragma unroll
        for (int n = 0; n < 8; ++n) {
            bf16x8 bfr = *(const bf16x8*)(sbh + (((n * 8 + ks) * 64 + lane) << 3));
            acc[n] = __builtin_amdgcn_mfma_f32_16x16x32_bf16(ab[ks], bfr, acc[n], 0, 0, 0);
        }
    }

    unsigned* op = sup32 + (long)tile * 16 * 64;
#pragma unroll
    for (int r = 0; r < 4; ++r) {
#pragma unroll
        for (int n = 0; n < 4; ++n) {
            __bf16 lo = (__bf16)acc[n][r], hi = (__bf16)acc[n + 4][r];
            unsigned w = (unsigned)*(unsigned short*)&lo |
                         ((unsigned)*(unsigned short*)&hi << 16);
            op[(quad * 4 + r) * 64 + n * 16 + m] = w;
        }
    }
}

// ---------------------------------------------------------------------------
// k_sg (R14): 512 bins of 98 rows, 512-thread blocks, launch_bounds(512,4)
// -> VGPR cap 128 (R13's 16-wide gather spilled at the 1024-thread clamp:
// VGPR_Count was 32).  16 sup-gathers in flight, all arrays register-resident.
// ---------------------------------------------------------------------------
__global__ __launch_bounds__(512, 4) void k_sg(const int* __restrict__ bin_cursor,
                                               const int2* __restrict__ binbuf,
                                               const unsigned* __restrict__ sup,
                                               const float* __restrict__ bias,
                                               float* __restrict__ out) {
    __shared__ int2 stage[BIN_CAP];                // 15 KB
    __shared__ int2 sorted_[BIN_CAP];              // 15 KB
    __shared__ int  cnt[128], off[128], cur[128], s[128];
    int b = blockIdx.x, t = threadIdx.x;
    int row0 = b * ROWS_PER_BIN;

    int n = bin_cursor[b * CUR_STRIDE] - b * BIN_CAP;
    n = n < 0 ? 0 : (n > BIN_CAP ? BIN_CAP : n);
    const int2* seg = binbuf + (long)b * BIN_CAP;

    if (t < 128) cnt[t] = 0;
    __syncthreads();

    for (int i = t; i < n; i += 512) {
        int2 rec = seg[i];
        stage[i] = rec;
        atomicAdd(&cnt[(int)(((unsigned)rec.x) >> 16) - row0], 1);
    }
    __syncthreads();

    int v = 0;
    if (t < 128) { v = cnt[t]; s[t] = v; }
    __syncthreads();
#pragma unroll
    for (int o = 1; o < 128; o <<= 1) {
        int xv = 0;
        if (t < 128 && t >= o) xv = s[t - o];
        __syncthreads();
        if (t < 128) s[t] += xv;
        __syncthreads();
    }
    if (t < 128) { off[t] = s[t] - v; cur[t] = 0; }
    __syncthreads();

    for (int i = t; i < n; i += 512) {
        int2 rec = stage[i];
        int rl = (int)(((unsigned)rec.x) >> 16) - row0;
        sorted_[off[rl] + atomicAdd(&cur[rl], 1)] = rec;
    }
    __syncthreads();

    int wave = t >> 6, lane = t & 63;
    float bb0 = bias[lane], bb1 = bias[64 + lane];

    for (int rl = wave; rl < ROWS_PER_BIN; rl += 8) {
        int row = row0 + rl;
        if (row >= N_NODES) continue;
        int st = off[rl], nd = cnt[rl];
        float a0 = 0.f, a1 = 0.f;
        for (int i = 0; i < nd; i += 16) {
            int cidx[16]; unsigned u[16]; float vv[16];
#pragma unroll
            for (int j = 0; j < 16; ++j) {
                int ok = (i + j) < nd;
                int2 rec = sorted_[ok ? st + i + j : st];
                cidx[j] = rec.x & 0xffff;
                vv[j]   = ok ? __int_as_float(rec.y) : 0.f;
            }
#pragma unroll
            for (int j = 0; j < 16; ++j)
                u[j] = sup[(long)cidx[j] * 64 + lane];
#pragma unroll
            for (int j = 0; j < 16; ++j) {
                a0 += vv[j] * blo(u[j]);
                a1 += vv[j] * bhi(u[j]);
            }
        }
        out[(long)row * 128 + lane]      = a0 + bb0;
        out[(long)row * 128 + 64 + lane] = a1 + bb1;
    }
}

// ---------------------------------------------------------------------------
extern "C" void kernel_launch(void* const* d_in, const int* in_sizes, int n_in,
                              void* d_out, int out_size, void* d_ws, size_t ws_size,
                              hipStream_t stream) {
    const int*   adj_rows = (const int*)  d_in[0];
    const int*   adj_cols = (const int*)  d_in[1];
    const float* adj_vals = (const float*)d_in[2];
    const float* x        = (const float*)d_in[3];
    const float* W        = (const float*)d_in[4];
    const float* b        = (const float*)d_in[5];
    float* out = (float*)d_out;

    char* ws = (char*)d_ws;
    __bf16*   Wf         = (__bf16*)  (ws + WF_OFF);
    unsigned* sup32      = (unsigned*)(ws + SUP_OFF);
    int2*     binbuf     = (int2*)    (ws + BIN_OFF);
    int*      bin_cursor = (int*)     (ws + CUR_OFF);

    k_prep<<<128, 256, 0, stream>>>(W, Wf, bin_cursor);
    k_bin <<<NB_BIN, 256, 0, stream>>>(adj_rows, adj_cols, adj_vals,
                                       bin_cursor, binbuf);
    k_gemm<<<NB_GEMM, 256, 0, stream>>>(x, Wf, sup32);
    k_sg  <<<NBINS, 512, 0, stream>>>(bin_cursor, binbuf, sup32, b, out);
}

// Round 7
// 155.777 us; speedup vs baseline: 1.1663x; 1.0445x over previous
//
#include <hip/hip_runtime.h>
#include <hip/hip_bf16.h>

#define N_NODES 50000
#define N_EDGES 800000
#define IN_DIM  256
#define OUT_DIM 128

#define NBINS        512      // bins of 98 rows: 512*98 = 50176 >= 50000
#define ROWS_PER_BIN 98
#define BIN_CAP      1920     // mean 1563 + 9 sigma
#define EPB          2048     // edges per bin-block
#define NB_BIN       391      // ceil(800000/2048)
#define NB_GEMM      782      // 1 wave = 1 tile, 4 tiles/block (R12, verified)
#define CUR_STRIDE   32       // one 128B cacheline per bin cursor

typedef __bf16 bf16x8 __attribute__((ext_vector_type(8)));
typedef float  f32x4  __attribute__((ext_vector_type(4)));

// bin = floor(row/98) via magic: (r*85599)>>23, exact for r < 50176 (verified R14;
// same constant as the R5-R7 /196 magic with shift 24->23).
__device__ __forceinline__ unsigned bin_of(unsigned r) { return (r * 85599u) >> 23; }
__device__ __forceinline__ float blo(unsigned u) { return __uint_as_float(u << 16); }
__device__ __forceinline__ float bhi(unsigned u) { return __uint_as_float(u & 0xffff0000u); }

// ---------------------------------------------------------------------------
// ws layout (bytes)
// ---------------------------------------------------------------------------
#define WF_OFF   0                      // 64 KB    : Wf bf16 frag-order [4096 slots][8]
#define SUP_OFF  65536                  // 12.8 MB  : support u32 [50000][64] planar-pair
#define BIN_OFF  12865536               // 7.86 MB  : binbuf int2[512*1920]
#define CUR_OFF  20729856               // 64 KB    : bin_cursor int[512*CUR_STRIDE]

// ---------------------------------------------------------------------------
// prep (R12, verified): Wf = W in MFMA B-fragment order.
// Slot s (16B = 8 halfs): n = s>>9, ks = (s>>6)&7, lane = s&63, m = lane&15,
// quad = (lane>>4); half j holds W[(quad*8+ks*32+j)*OUT_DIM + (n*16+m)].
// ---------------------------------------------------------------------------
__global__ void k_prep(const float* __restrict__ W, __bf16* __restrict__ Wf,
                       int* __restrict__ bin_cursor) {
    int t = blockIdx.x * 256 + threadIdx.x;
    if (t < 32768) {
        int s = t >> 3, j = t & 7;
        int nrow = ((s >> 9) << 4) | (s & 15);                 // n*16 + m
        int k    = (((s >> 4) & 3) << 3) | (((s >> 6) & 7) << 5) | j;
        Wf[t] = (__bf16)W[k * OUT_DIM + nrow];
    }
    if (t < NBINS) bin_cursor[t * CUR_STRIDE] = t * BIN_CAP;
}

// ---------------------------------------------------------------------------
// k_fuse (R15): gemm and bin are INDEPENDENT -> one dispatch, block-range
// specialized, so they co-run on the CUs (bin is latency/atomic-bound, gemm
// is BW/MFMA-bound -- complementary).  Gemm blocks first (the longer pole).
//   blocks [0, NB_GEMM):        verified R12 gemm body, verbatim.
//   blocks [NB_GEMM, +NB_BIN):  verified R14 bin body, verbatim.
// ---------------------------------------------------------------------------
__global__ __launch_bounds__(256, 2) void k_fuse(const float* __restrict__ x,
                                                 const __bf16* __restrict__ Wf,
                                                 unsigned* __restrict__ sup32,
                                                 const int* __restrict__ rows,
                                                 const int* __restrict__ cols,
                                                 const float* __restrict__ vals,
                                                 int* __restrict__ bin_cursor,
                                                 int2* __restrict__ binbuf) {
    __shared__ union {
        uint4 sB[4096];                                   // 64 KB : gemm Wf tile
        struct { int cur[NBINS]; int base[NBINS]; } bin;  // 4 KB  : bin counters
    } sh;
    int t = threadIdx.x;

    if (blockIdx.x < NB_GEMM) {
        // ---------------- gemm path (R12, verified) ----------------
        const uint4* wf4 = (const uint4*)Wf;
#pragma unroll
        for (int r = 0; r < 16; ++r) sh.sB[r * 256 + t] = wf4[r * 256 + t];
        __syncthreads();

        int  wave = t >> 6;
        int  lane = t & 63;
        long tile = (long)blockIdx.x * 4 + wave;       // 0..3127
        if (tile >= 3125) return;                      // after the barrier: safe
        int  m    = lane & 15;
        int  quad = lane >> 4;

        // A: lane (m,quad) reads row tile*16+m; 3125*16 == 50000 -> no guard.
        const float* aprow = x + (tile * 16 + m) * IN_DIM + quad * 8;

        float4 fa[16];
#pragma unroll
        for (int ks = 0; ks < 8; ++ks) {
            fa[2 * ks]     = *(const float4*)(aprow + ks * 32);
            fa[2 * ks + 1] = *(const float4*)(aprow + ks * 32 + 4);
        }
        bf16x8 ab[8];
#pragma unroll
        for (int ks = 0; ks < 8; ++ks) {
            float4 f0 = fa[2 * ks];
            float4 f1 = fa[2 * ks + 1];
            ab[ks] = (bf16x8){(__bf16)f0.x, (__bf16)f0.y, (__bf16)f0.z, (__bf16)f0.w,
                              (__bf16)f1.x, (__bf16)f1.y, (__bf16)f1.z, (__bf16)f1.w};
        }

        f32x4 acc[8];
#pragma unroll
        for (int n = 0; n < 8; ++n) acc[n] = (f32x4){0, 0, 0, 0};

        const __bf16* sbh = (const __bf16*)sh.sB;
#pragma unroll
        for (int ks = 0; ks < 8; ++ks) {
#pragma unroll
            for (int n = 0; n < 8; ++n) {
                // slot (n*8+ks)*64 + lane : consecutive lanes -> consecutive 16B
                bf16x8 bfr = *(const bf16x8*)(sbh + (((n * 8 + ks) * 64 + lane) << 3));
                acc[n] = __builtin_amdgcn_mfma_f32_16x16x32_bf16(ab[ks], bfr, acc[n], 0, 0, 0);
            }
        }

        // planar-pair epilogue (verified R7): word j = n*16+m = ch j | ch j+64
        unsigned* op = sup32 + (long)tile * 16 * 64;
#pragma unroll
        for (int r = 0; r < 4; ++r) {
#pragma unroll
            for (int n = 0; n < 4; ++n) {
                __bf16 lo = (__bf16)acc[n][r], hi = (__bf16)acc[n + 4][r];
                unsigned w = (unsigned)*(unsigned short*)&lo |
                             ((unsigned)*(unsigned short*)&hi << 16);
                op[(quad * 4 + r) * 64 + n * 16 + m] = w;
            }
        }
    } else {
        // ---------------- bin path (R14, verified) ----------------
        long e0 = (long)(blockIdx.x - NB_GEMM) * EPB;
        sh.bin.cur[t] = 0; sh.bin.cur[t + 256] = 0;
        __syncthreads();

        int2 rec[8];
        int  lrank[8];
        bool full = (e0 + EPB <= N_EDGES);   // true for 390 of 391 blocks

        if (full) {
#pragma unroll
            for (int k = 0; k < 8; ++k) {
                long e = e0 + k * 256 + t;
                unsigned r = (unsigned)rows[e];
                unsigned c = (unsigned)cols[e];
                float    w = vals[e];
                rec[k]   = make_int2((int)((r << 16) | c), __float_as_int(w));
                lrank[k] = atomicAdd(&sh.bin.cur[bin_of(r)], 1);
            }
        } else {
#pragma unroll
            for (int k = 0; k < 8; ++k) {
                long e = e0 + k * 256 + t;
                lrank[k] = -1;
                if (e < N_EDGES) {
                    unsigned r = (unsigned)rows[e];
                    unsigned c = (unsigned)cols[e];
                    float    w = vals[e];
                    rec[k]   = make_int2((int)((r << 16) | c), __float_as_int(w));
                    lrank[k] = atomicAdd(&sh.bin.cur[bin_of(r)], 1);
                }
            }
        }
        __syncthreads();

        sh.bin.base[t]       = atomicAdd(&bin_cursor[t * CUR_STRIDE],         sh.bin.cur[t]);
        sh.bin.base[t + 256] = atomicAdd(&bin_cursor[(t + 256) * CUR_STRIDE], sh.bin.cur[t + 256]);
        __syncthreads();

        if (full) {
#pragma unroll
            for (int k = 0; k < 8; ++k) {
                unsigned bn = bin_of(((unsigned)rec[k].x) >> 16);
                int dst = sh.bin.base[bn] + lrank[k];
                if (dst < (int)(bn + 1) * BIN_CAP)
                    binbuf[dst] = rec[k];
            }
        } else {
#pragma unroll
            for (int k = 0; k < 8; ++k) {
                if (lrank[k] >= 0) {
                    unsigned bn = bin_of(((unsigned)rec[k].x) >> 16);
                    int dst = sh.bin.base[bn] + lrank[k];
                    if (dst < (int)(bn + 1) * BIN_CAP)
                        binbuf[dst] = rec[k];
                }
            }
        }
    }
}

// ---------------------------------------------------------------------------
// k_sg (R14, verified): 512 bins of 98 rows, 512-thread blocks,
// launch_bounds(512,4) -> VGPR cap 128 so the 16-wide gather window stays
// register-resident.
// ---------------------------------------------------------------------------
__global__ __launch_bounds__(512, 4) void k_sg(const int* __restrict__ bin_cursor,
                                               const int2* __restrict__ binbuf,
                                               const unsigned* __restrict__ sup,
                                               const float* __restrict__ bias,
                                               float* __restrict__ out) {
    __shared__ int2 stage[BIN_CAP];                // 15 KB
    __shared__ int2 sorted_[BIN_CAP];              // 15 KB
    __shared__ int  cnt[128], off[128], cur[128], s[128];
    int b = blockIdx.x, t = threadIdx.x;
    int row0 = b * ROWS_PER_BIN;

    int n = bin_cursor[b * CUR_STRIDE] - b * BIN_CAP;
    n = n < 0 ? 0 : (n > BIN_CAP ? BIN_CAP : n);
    const int2* seg = binbuf + (long)b * BIN_CAP;

    if (t < 128) cnt[t] = 0;
    __syncthreads();

    for (int i = t; i < n; i += 512) {
        int2 rec = seg[i];
        stage[i] = rec;
        atomicAdd(&cnt[(int)(((unsigned)rec.x) >> 16) - row0], 1);
    }
    __syncthreads();

    int v = 0;
    if (t < 128) { v = cnt[t]; s[t] = v; }
    __syncthreads();
#pragma unroll
    for (int o = 1; o < 128; o <<= 1) {
        int xv = 0;
        if (t < 128 && t >= o) xv = s[t - o];
        __syncthreads();
        if (t < 128) s[t] += xv;
        __syncthreads();
    }
    if (t < 128) { off[t] = s[t] - v; cur[t] = 0; }
    __syncthreads();

    for (int i = t; i < n; i += 512) {
        int2 rec = stage[i];
        int rl = (int)(((unsigned)rec.x) >> 16) - row0;
        sorted_[off[rl] + atomicAdd(&cur[rl], 1)] = rec;
    }
    __syncthreads();

    int wave = t >> 6, lane = t & 63;
    float bb0 = bias[lane], bb1 = bias[64 + lane];

    for (int rl = wave; rl < ROWS_PER_BIN; rl += 8) {
        int row = row0 + rl;
        if (row >= N_NODES) continue;
        int st = off[rl], nd = cnt[rl];
        float a0 = 0.f, a1 = 0.f;
        for (int i = 0; i < nd; i += 16) {
            int cidx[16]; unsigned u[16]; float vv[16];
#pragma unroll
            for (int j = 0; j < 16; ++j) {
                int ok = (i + j) < nd;
                int2 rec = sorted_[ok ? st + i + j : st];
                cidx[j] = rec.x & 0xffff;
                vv[j]   = ok ? __int_as_float(rec.y) : 0.f;
            }
#pragma unroll
            for (int j = 0; j < 16; ++j)
                u[j] = sup[(long)cidx[j] * 64 + lane];
#pragma unroll
            for (int j = 0; j < 16; ++j) {
                a0 += vv[j] * blo(u[j]);
                a1 += vv[j] * bhi(u[j]);
            }
        }
        out[(long)row * 128 + lane]      = a0 + bb0;
        out[(long)row * 128 + 64 + lane] = a1 + bb1;
    }
}

// ---------------------------------------------------------------------------
extern "C" void kernel_launch(void* const* d_in, const int* in_sizes, int n_in,
                              void* d_out, int out_size, void* d_ws, size_t ws_size,
                              hipStream_t stream) {
    const int*   adj_rows = (const int*)  d_in[0];
    const int*   adj_cols = (const int*)  d_in[1];
    const float* adj_vals = (const float*)d_in[2];
    const float* x        = (const float*)d_in[3];
    const float* W        = (const float*)d_in[4];
    const float* b        = (const float*)d_in[5];
    float* out = (float*)d_out;

    char* ws = (char*)d_ws;
    __bf16*   Wf         = (__bf16*)  (ws + WF_OFF);
    unsigned* sup32      = (unsigned*)(ws + SUP_OFF);
    int2*     binbuf     = (int2*)    (ws + BIN_OFF);
    int*      bin_cursor = (int*)     (ws + CUR_OFF);

    k_prep<<<128, 256, 0, stream>>>(W, Wf, bin_cursor);
    k_fuse<<<NB_GEMM + NB_BIN, 256, 0, stream>>>(x, Wf, sup32,
                                                 adj_rows, adj_cols, adj_vals,
                                                 bin_cursor, binbuf);
    k_sg  <<<NBINS, 512, 0, stream>>>(bin_cursor, binbuf, sup32, b, out);
}